// Round 4
// baseline (618.782 us; speedup 1.0000x reference)
//
#include <hip/hip_runtime.h>
#include <hip/hip_fp16.h>
#include <math.h>

#define VV 5
#define CC 16
#define DD 32
#define HH 256
#define WW 320
#define HW (HH*WW)
#define ND 8            // depths per thread in k_var
#define DSEG 8          // depths per thread in k_conv
#define YSEG 2          // rows per thread in k_conv
#define NXCD 8

// ---------------------------------------------------------------------------
// Kernel 1: projection setup (single thread). For each src view v=1..4:
// proj = mk_proj(p_v) @ inv(mk_proj(p_0)); store rot(3x3)+trans(3) in M.
// ---------------------------------------------------------------------------
__global__ void k_setup(const float* __restrict__ projs, float* __restrict__ M) {
    if (threadIdx.x != 0 || blockIdx.x != 0) return;

    float ref[16];
    {
        const float* E = projs + 0 * 32;
        const float* K = projs + 0 * 32 + 16;
        for (int i = 0; i < 16; i++) ref[i] = E[i];
        for (int i = 0; i < 3; i++)
            for (int j = 0; j < 4; j++) {
                float s = 0.f;
                for (int k = 0; k < 3; k++) s += K[i*4+k] * E[k*4+j];
                ref[i*4+j] = s;
            }
    }

    float a[16], inv[16];
    for (int i = 0; i < 16; i++) { a[i] = ref[i]; inv[i] = ((i % 5) == 0) ? 1.f : 0.f; }
    for (int col = 0; col < 4; col++) {
        int piv = col; float best = fabsf(a[col*4+col]);
        for (int r = col+1; r < 4; r++) {
            float v = fabsf(a[r*4+col]);
            if (v > best) { best = v; piv = r; }
        }
        if (piv != col) {
            for (int j = 0; j < 4; j++) {
                float t = a[col*4+j]; a[col*4+j] = a[piv*4+j]; a[piv*4+j] = t;
                t = inv[col*4+j]; inv[col*4+j] = inv[piv*4+j]; inv[piv*4+j] = t;
            }
        }
        float rd = 1.f / a[col*4+col];
        for (int j = 0; j < 4; j++) { a[col*4+j] *= rd; inv[col*4+j] *= rd; }
        for (int r = 0; r < 4; r++) {
            if (r == col) continue;
            float f = a[r*4+col];
            for (int j = 0; j < 4; j++) {
                a[r*4+j]   -= f * a[col*4+j];
                inv[r*4+j] -= f * inv[col*4+j];
            }
        }
    }

    for (int v = 1; v < VV; v++) {
        float s[16], p[16];
        const float* E = projs + v * 32;
        const float* K = projs + v * 32 + 16;
        for (int i = 0; i < 16; i++) s[i] = E[i];
        for (int i = 0; i < 3; i++)
            for (int j = 0; j < 4; j++) {
                float acc = 0.f;
                for (int k = 0; k < 3; k++) acc += K[i*4+k] * E[k*4+j];
                s[i*4+j] = acc;
            }
        for (int i = 0; i < 4; i++)
            for (int j = 0; j < 4; j++) {
                float acc = 0.f;
                for (int k = 0; k < 4; k++) acc += s[i*4+k] * inv[k*4+j];
                p[i*4+j] = acc;
            }
        float* o = M + (v - 1) * 12;
        o[0] = p[0];  o[1] = p[1];  o[2]  = p[2];
        o[3] = p[4];  o[4] = p[5];  o[5]  = p[6];
        o[6] = p[8];  o[7] = p[9];  o[8]  = p[10];
        o[9] = p[3];  o[10] = p[7]; o[11] = p[11];
    }
}

// ---------------------------------------------------------------------------
// Kernel 1b: transpose features [V][C][H][W] -> [V][H*W][C] as fp16.
// ---------------------------------------------------------------------------
union H8 { float4 f4; __half2 h2[4]; };

__global__ __launch_bounds__(256) void k_transpose(const float* __restrict__ feat,
                                                   __half* __restrict__ tf) {
    const int idx = blockIdx.x * 256 + threadIdx.x;   // over V*HW
    if (idx >= VV * HW) return;
    const int v = idx / HW;
    const int pix = idx - v * HW;
    const float* src = feat + (size_t)v * CC * HW + pix;
    float t[CC];
    #pragma unroll
    for (int c = 0; c < CC; c++) t[c] = src[(size_t)c * HW];
    H8 o0, o1;
    #pragma unroll
    for (int g = 0; g < 4; g++) o0.h2[g] = __floats2half2_rn(t[2*g],     t[2*g+1]);
    #pragma unroll
    for (int g = 0; g < 4; g++) o1.h2[g] = __floats2half2_rn(t[8 + 2*g], t[8 + 2*g + 1]);
    float4* dst = (float4*)(tf + (size_t)idx * CC);
    dst[0] = o0.f4;
    dst[1] = o1.f4;
}

// ---------------------------------------------------------------------------
// Kernel 2: variance volume from fp16 channel-last features, ND depths per
// thread, XCD-chunked block swizzle (XCD k owns a contiguous 32-row band
// across all depth groups -> tf rows + depth_vals fit its private L2).
// ---------------------------------------------------------------------------
__global__ __launch_bounds__(320) void k_var_t(const __half* __restrict__ tf,
                                               const float* __restrict__ depth_vals,
                                               const float* __restrict__ M,
                                               __half* __restrict__ var) {
    // bijective chunked XCD swizzle: gridDim.x = 1024 = 8 chunks of 128
    const int orig = blockIdx.x;
    const int wg   = (orig & (NXCD - 1)) * 128 + (orig >> 3);
    const int chunk = wg >> 7;          // 0..7
    const int i     = wg & 127;
    const int y  = chunk * 32 + (i & 31);
    const int dg = i >> 5;              // 0..3

    const int x = threadIdx.x;
    const int pix = y * WW + x;

    // reference features (view 0), f32
    float ref[CC];
    {
        const float4* r0 = (const float4*)(tf + (size_t)pix * CC);
        H8 a, b; a.f4 = r0[0]; b.f4 = r0[1];
        #pragma unroll
        for (int g = 0; g < 4; g++) {
            ref[2*g]     = __low2float(a.h2[g]);  ref[2*g+1]     = __high2float(a.h2[g]);
            ref[8 + 2*g] = __low2float(b.h2[g]);  ref[8 + 2*g+1] = __high2float(b.h2[g]);
        }
    }

    // hoist depth-independent projection rows per view
    const float fx = (float)x, fy = (float)y;
    float ax[4], ay[4], az[4], bx[4], by[4], bz[4];
    #pragma unroll
    for (int v = 0; v < 4; v++) {
        const float* m = M + v * 12;
        ax[v] = m[0]*fx + m[1]*fy + m[2];
        ay[v] = m[3]*fx + m[4]*fy + m[5];
        az[v] = m[6]*fx + m[7]*fy + m[8];
        bx[v] = m[9]; by[v] = m[10]; bz[v] = m[11];
    }

    #pragma unroll
    for (int dl = 0; dl < ND; dl++) {
        const int d = dg * ND + dl;
        const float depth = depth_vals[(size_t)d * HW + pix];

        float sum[CC], sq[CC];
        #pragma unroll
        for (int c = 0; c < CC; c++) { sum[c] = ref[c]; sq[c] = ref[c] * ref[c]; }

        #pragma unroll
        for (int v = 0; v < 4; v++) {
            float px = ax[v] * depth + bx[v];
            float py = ay[v] * depth + by[v];
            float pz = az[v] * depth + bz[v];
            px = px / pz;
            py = py / pz;

            float x0f = floorf(px), y0f = floorf(py);
            float wx = px - x0f,    wy = py - y0f;
            int x0 = (int)x0f, y0 = (int)y0f;
            int x1 = x0 + 1,   y1 = y0 + 1;

            float mx0 = (x0 >= 0 && x0 < WW) ? 1.f : 0.f;
            float mx1 = (x1 >= 0 && x1 < WW) ? 1.f : 0.f;
            float my0 = (y0 >= 0 && y0 < HH) ? 1.f : 0.f;
            float my1 = (y1 >= 0 && y1 < HH) ? 1.f : 0.f;

            int cx0 = min(max(x0, 0), WW - 1), cx1 = min(max(x1, 0), WW - 1);
            int cy0 = min(max(y0, 0), HH - 1), cy1 = min(max(y1, 0), HH - 1);

            float f00 = (1.f - wx) * (1.f - wy) * mx0 * my0;
            float f01 = wx * (1.f - wy)         * mx1 * my0;
            float f10 = (1.f - wx) * wy         * mx0 * my1;
            float f11 = wx * wy                 * mx1 * my1;

            int i00 = cy0 * WW + cx0, i01 = cy0 * WW + cx1;
            int i10 = cy1 * WW + cx0, i11 = cy1 * WW + cx1;

            const __half* tfv = tf + (size_t)(v + 1) * HW * CC;
            float wv[CC];
            #pragma unroll
            for (int c = 0; c < CC; c++) wv[c] = 0.f;

            #define GATHER_CORNER(IDX, F) { \
                const float4* p4 = (const float4*)(tfv + (size_t)(IDX) * CC); \
                H8 ua, ub; ua.f4 = p4[0]; ub.f4 = p4[1]; \
                _Pragma("unroll") \
                for (int g = 0; g < 4; g++) { \
                    wv[2*g]       += (F) * __low2float(ua.h2[g]); \
                    wv[2*g+1]     += (F) * __high2float(ua.h2[g]); \
                    wv[8 + 2*g]   += (F) * __low2float(ub.h2[g]); \
                    wv[8 + 2*g+1] += (F) * __high2float(ub.h2[g]); \
                } }

            GATHER_CORNER(i00, f00)
            GATHER_CORNER(i01, f01)
            GATHER_CORNER(i10, f10)
            GATHER_CORNER(i11, f11)
            #undef GATHER_CORNER

            #pragma unroll
            for (int c = 0; c < CC; c++) {
                sum[c] += wv[c];
                sq[c]  += wv[c] * wv[c];
            }
        }

        const float invV = 1.f / (float)VV;
        #pragma unroll
        for (int c = 0; c < CC; c++) {
            float mean = sum[c] * invV;
            var[(size_t)c * DD * HW + (size_t)d * HW + pix] =
                __float2half(sq[c] * invV - mean * mean);
        }
    }
}

// ---------------------------------------------------------------------------
// Kernel 3: 3D conv (16->1, 3x3x3, SAME) on fp16 var. Each thread: YSEG rows
// x DSEG depths at fixed x. Rolling depth window; XCD-chunked swizzle.
// ---------------------------------------------------------------------------
__global__ __launch_bounds__(320) void k_conv(const __half* __restrict__ var,
                                              const float* __restrict__ w,
                                              float* __restrict__ cost) {
    // gridDim.x = 512 = 8 chunks of 64
    const int orig = blockIdx.x;
    const int wg   = (orig & (NXCD - 1)) * 64 + (orig >> 3);
    const int chunk = wg >> 6;          // 0..7
    const int i     = wg & 63;
    const int y0 = (chunk * 16 + (i & 15)) * YSEG;
    const int d0 = (i >> 4) * DSEG;

    const int x = threadIdx.x;

    float acc[YSEG][DSEG];
    #pragma unroll
    for (int dy = 0; dy < YSEG; dy++)
        #pragma unroll
        for (int o = 0; o < DSEG; o++) acc[dy][o] = 0.f;

    const bool xlok = (x > 0), xrok = (x < WW - 1);

    for (int c = 0; c < CC; c++) {
        float wr[27];
        #pragma unroll
        for (int j = 0; j < 27; j++) wr[j] = w[c * 27 + j];   // uniform -> SGPR

        const __half* base = var + (size_t)c * DD * HW;

        #pragma unroll
        for (int s = 0; s < DSEG + 2; s++) {
            const int dd = d0 - 1 + s;
            if (dd < 0 || dd >= DD) continue;               // uniform branch

            float v[YSEG + 2][3];
            #pragma unroll
            for (int r = 0; r < YSEG + 2; r++) {
                const int yy = y0 - 1 + r;
                if (yy < 0 || yy >= HH) {                    // uniform per block
                    v[r][0] = v[r][1] = v[r][2] = 0.f;
                } else {
                    const __half* pr = base + (size_t)dd * HW + (size_t)yy * WW + x;
                    v[r][1] = __half2float(pr[0]);
                    v[r][0] = xlok ? __half2float(pr[-1]) : 0.f;
                    v[r][2] = xrok ? __half2float(pr[ 1]) : 0.f;
                }
            }

            #pragma unroll
            for (int dy = 0; dy < YSEG; dy++) {
                #pragma unroll
                for (int kd = 0; kd < 3; kd++) {
                    const int o = s - kd;
                    if (o < 0 || o >= DSEG) continue;        // compile-time
                    const float* k9 = wr + kd * 9;
                    acc[dy][o] += k9[0]*v[dy+0][0] + k9[1]*v[dy+0][1] + k9[2]*v[dy+0][2]
                                + k9[3]*v[dy+1][0] + k9[4]*v[dy+1][1] + k9[5]*v[dy+1][2]
                                + k9[6]*v[dy+2][0] + k9[7]*v[dy+2][1] + k9[8]*v[dy+2][2];
                }
            }
        }
    }

    #pragma unroll
    for (int dy = 0; dy < YSEG; dy++) {
        const int pix = (y0 + dy) * WW + x;
        #pragma unroll
        for (int o = 0; o < DSEG; o++)
            cost[(size_t)(d0 + o) * HW + pix] = acc[dy][o];
    }
}

// ---------------------------------------------------------------------------
// Kernel 4: softmax over D + depth regression + confidence.
// out layout: [0,HW) depth | [HW,2HW) conf | [2HW, 2HW+D*HW) prob
// ---------------------------------------------------------------------------
__global__ __launch_bounds__(256) void k_softmax(const float* __restrict__ cost,
                                                 const float* __restrict__ depth_vals,
                                                 float* __restrict__ out) {
    const int idx = blockIdx.x * blockDim.x + threadIdx.x;
    if (idx >= HW) return;

    float c[DD];
    float m = -INFINITY;
    #pragma unroll
    for (int d = 0; d < DD; d++) {
        c[d] = cost[(size_t)d * HW + idx];
        m = fmaxf(m, c[d]);
    }
    float s = 0.f;
    #pragma unroll
    for (int d = 0; d < DD; d++) {
        c[d] = expf(c[d] - m);
        s += c[d];
    }
    const float inv = 1.f / s;

    float depth = 0.f, di_f = 0.f;
    #pragma unroll
    for (int d = 0; d < DD; d++) {
        float p = c[d] * inv;
        c[d] = p;
        out[2 * HW + (size_t)d * HW + idx] = p;
        depth += p * depth_vals[(size_t)d * HW + idx];
        di_f  += p * (float)d;
    }
    out[idx] = depth;

    int di = (int)di_f;
    di = min(max(di, 0), DD - 1);
    float cur = 0.f, nxt = 0.f;
    #pragma unroll
    for (int d = 0; d < DD; d++) {
        if (d == di)     cur = c[d];
        if (d == di + 1) nxt = c[d];
    }
    out[HW + idx] = cur + nxt;   // nxt stays 0 when di == DD-1
}

// ---------------------------------------------------------------------------
extern "C" void kernel_launch(void* const* d_in, const int* in_sizes, int n_in,
                              void* d_out, int out_size, void* d_ws, size_t ws_size,
                              hipStream_t stream) {
    const float* features = (const float*)d_in[0];
    const float* projs    = (const float*)d_in[1];
    const float* depthv   = (const float*)d_in[2];
    const float* regw     = (const float*)d_in[3];
    float* out = (float*)d_out;

    const size_t tf_elems  = (size_t)VV * HW * CC;       // 6.55M halves (13.1 MB)
    // var: CC*DD*HW halves (83.9 MB)

    float*  M    = (float*)d_ws;                         // 48 floats used
    __half* tf   = (__half*)((char*)d_ws + 4096);
    __half* var  = tf + tf_elems;
    float*  cost = (float*)tf;                           // tf dead after k_var (13.1 >= 10.5 MB)

    k_setup<<<1, 64, 0, stream>>>(projs, M);
    k_transpose<<<(VV * HW + 255) / 256, 256, 0, stream>>>(features, tf);

    k_var_t<<<HH * (DD / ND), WW, 0, stream>>>(tf, depthv, M, var);

    k_conv<<<(HH / YSEG) * (DD / DSEG), WW, 0, stream>>>(var, regw, cost);

    k_softmax<<<(HW + 255) / 256, 256, 0, stream>>>(cost, depthv, out);
}

// Round 5
// 430.042 us; speedup vs baseline: 1.4389x; 1.4389x over previous
//
#include <hip/hip_runtime.h>
#include <hip/hip_fp16.h>
#include <math.h>

#define VV 5
#define CC 16
#define DD 32
#define HH 256
#define WW 320
#define HW (HH*WW)
#define ND 8            // depths per thread in k_var
#define CDSEG 4         // depths per thread in k_conv
#define YSEG 2          // rows per thread in k_conv
#define NXCD 8

// ---------------------------------------------------------------------------
// Kernel 1: projection setup (single thread). For each src view v=1..4:
// proj = mk_proj(p_v) @ inv(mk_proj(p_0)); store rot(3x3)+trans(3) in M.
// ---------------------------------------------------------------------------
__global__ void k_setup(const float* __restrict__ projs, float* __restrict__ M) {
    if (threadIdx.x != 0 || blockIdx.x != 0) return;

    float ref[16];
    {
        const float* E = projs + 0 * 32;
        const float* K = projs + 0 * 32 + 16;
        for (int i = 0; i < 16; i++) ref[i] = E[i];
        for (int i = 0; i < 3; i++)
            for (int j = 0; j < 4; j++) {
                float s = 0.f;
                for (int k = 0; k < 3; k++) s += K[i*4+k] * E[k*4+j];
                ref[i*4+j] = s;
            }
    }

    float a[16], inv[16];
    for (int i = 0; i < 16; i++) { a[i] = ref[i]; inv[i] = ((i % 5) == 0) ? 1.f : 0.f; }
    for (int col = 0; col < 4; col++) {
        int piv = col; float best = fabsf(a[col*4+col]);
        for (int r = col+1; r < 4; r++) {
            float v = fabsf(a[r*4+col]);
            if (v > best) { best = v; piv = r; }
        }
        if (piv != col) {
            for (int j = 0; j < 4; j++) {
                float t = a[col*4+j]; a[col*4+j] = a[piv*4+j]; a[piv*4+j] = t;
                t = inv[col*4+j]; inv[col*4+j] = inv[piv*4+j]; inv[piv*4+j] = t;
            }
        }
        float rd = 1.f / a[col*4+col];
        for (int j = 0; j < 4; j++) { a[col*4+j] *= rd; inv[col*4+j] *= rd; }
        for (int r = 0; r < 4; r++) {
            if (r == col) continue;
            float f = a[r*4+col];
            for (int j = 0; j < 4; j++) {
                a[r*4+j]   -= f * a[col*4+j];
                inv[r*4+j] -= f * inv[col*4+j];
            }
        }
    }

    for (int v = 1; v < VV; v++) {
        float s[16], p[16];
        const float* E = projs + v * 32;
        const float* K = projs + v * 32 + 16;
        for (int i = 0; i < 16; i++) s[i] = E[i];
        for (int i = 0; i < 3; i++)
            for (int j = 0; j < 4; j++) {
                float acc = 0.f;
                for (int k = 0; k < 3; k++) acc += K[i*4+k] * E[k*4+j];
                s[i*4+j] = acc;
            }
        for (int i = 0; i < 4; i++)
            for (int j = 0; j < 4; j++) {
                float acc = 0.f;
                for (int k = 0; k < 4; k++) acc += s[i*4+k] * inv[k*4+j];
                p[i*4+j] = acc;
            }
        float* o = M + (v - 1) * 12;
        o[0] = p[0];  o[1] = p[1];  o[2]  = p[2];
        o[3] = p[4];  o[4] = p[5];  o[5]  = p[6];
        o[6] = p[8];  o[7] = p[9];  o[8]  = p[10];
        o[9] = p[3];  o[10] = p[7]; o[11] = p[11];
    }
}

// ---------------------------------------------------------------------------
// Kernel 1b: transpose features [V][C][H][W] -> [V][H*W][C] as fp16.
// ---------------------------------------------------------------------------
union H8 { float4 f4; __half2 h2[4]; };

__global__ __launch_bounds__(256) void k_transpose(const float* __restrict__ feat,
                                                   __half* __restrict__ tf) {
    const int idx = blockIdx.x * 256 + threadIdx.x;   // over V*HW
    if (idx >= VV * HW) return;
    const int v = idx / HW;
    const int pix = idx - v * HW;
    const float* src = feat + (size_t)v * CC * HW + pix;
    float t[CC];
    #pragma unroll
    for (int c = 0; c < CC; c++) t[c] = src[(size_t)c * HW];
    H8 o0, o1;
    #pragma unroll
    for (int g = 0; g < 4; g++) o0.h2[g] = __floats2half2_rn(t[2*g],     t[2*g+1]);
    #pragma unroll
    for (int g = 0; g < 4; g++) o1.h2[g] = __floats2half2_rn(t[8 + 2*g], t[8 + 2*g + 1]);
    float4* dst = (float4*)(tf + (size_t)idx * CC);
    dst[0] = o0.f4;
    dst[1] = o1.f4;
}

// ---------------------------------------------------------------------------
// Kernel 2: variance volume from fp16 channel-last features, ND depths per
// thread, XCD-chunked block swizzle (XCD k owns a contiguous 32-row band
// across all depth groups -> tf rows + depth_vals fit its private L2).
// ---------------------------------------------------------------------------
__global__ __launch_bounds__(320) void k_var_t(const __half* __restrict__ tf,
                                               const float* __restrict__ depth_vals,
                                               const float* __restrict__ M,
                                               __half* __restrict__ var) {
    // bijective chunked XCD swizzle: gridDim.x = 1024 = 8 chunks of 128
    const int orig = blockIdx.x;
    const int wg   = (orig & (NXCD - 1)) * 128 + (orig >> 3);
    const int chunk = wg >> 7;          // 0..7
    const int i     = wg & 127;
    const int y  = chunk * 32 + (i & 31);
    const int dg = i >> 5;              // 0..3

    const int x = threadIdx.x;
    const int pix = y * WW + x;

    // reference features (view 0), f32
    float ref[CC];
    {
        const float4* r0 = (const float4*)(tf + (size_t)pix * CC);
        H8 a, b; a.f4 = r0[0]; b.f4 = r0[1];
        #pragma unroll
        for (int g = 0; g < 4; g++) {
            ref[2*g]     = __low2float(a.h2[g]);  ref[2*g+1]     = __high2float(a.h2[g]);
            ref[8 + 2*g] = __low2float(b.h2[g]);  ref[8 + 2*g+1] = __high2float(b.h2[g]);
        }
    }

    // hoist depth-independent projection rows per view
    const float fx = (float)x, fy = (float)y;
    float ax[4], ay[4], az[4], bx[4], by[4], bz[4];
    #pragma unroll
    for (int v = 0; v < 4; v++) {
        const float* m = M + v * 12;
        ax[v] = m[0]*fx + m[1]*fy + m[2];
        ay[v] = m[3]*fx + m[4]*fy + m[5];
        az[v] = m[6]*fx + m[7]*fy + m[8];
        bx[v] = m[9]; by[v] = m[10]; bz[v] = m[11];
    }

    #pragma unroll
    for (int dl = 0; dl < ND; dl++) {
        const int d = dg * ND + dl;
        const float depth = depth_vals[(size_t)d * HW + pix];

        float sum[CC], sq[CC];
        #pragma unroll
        for (int c = 0; c < CC; c++) { sum[c] = ref[c]; sq[c] = ref[c] * ref[c]; }

        #pragma unroll
        for (int v = 0; v < 4; v++) {
            float px = ax[v] * depth + bx[v];
            float py = ay[v] * depth + by[v];
            float pz = az[v] * depth + bz[v];
            px = px / pz;
            py = py / pz;

            float x0f = floorf(px), y0f = floorf(py);
            float wx = px - x0f,    wy = py - y0f;
            int x0 = (int)x0f, y0 = (int)y0f;
            int x1 = x0 + 1,   y1 = y0 + 1;

            float mx0 = (x0 >= 0 && x0 < WW) ? 1.f : 0.f;
            float mx1 = (x1 >= 0 && x1 < WW) ? 1.f : 0.f;
            float my0 = (y0 >= 0 && y0 < HH) ? 1.f : 0.f;
            float my1 = (y1 >= 0 && y1 < HH) ? 1.f : 0.f;

            int cx0 = min(max(x0, 0), WW - 1), cx1 = min(max(x1, 0), WW - 1);
            int cy0 = min(max(y0, 0), HH - 1), cy1 = min(max(y1, 0), HH - 1);

            float f00 = (1.f - wx) * (1.f - wy) * mx0 * my0;
            float f01 = wx * (1.f - wy)         * mx1 * my0;
            float f10 = (1.f - wx) * wy         * mx0 * my1;
            float f11 = wx * wy                 * mx1 * my1;

            int i00 = cy0 * WW + cx0, i01 = cy0 * WW + cx1;
            int i10 = cy1 * WW + cx0, i11 = cy1 * WW + cx1;

            const __half* tfv = tf + (size_t)(v + 1) * HW * CC;
            float wv[CC];
            #pragma unroll
            for (int c = 0; c < CC; c++) wv[c] = 0.f;

            #define GATHER_CORNER(IDX, F) { \
                const float4* p4 = (const float4*)(tfv + (size_t)(IDX) * CC); \
                H8 ua, ub; ua.f4 = p4[0]; ub.f4 = p4[1]; \
                _Pragma("unroll") \
                for (int g = 0; g < 4; g++) { \
                    wv[2*g]       += (F) * __low2float(ua.h2[g]); \
                    wv[2*g+1]     += (F) * __high2float(ua.h2[g]); \
                    wv[8 + 2*g]   += (F) * __low2float(ub.h2[g]); \
                    wv[8 + 2*g+1] += (F) * __high2float(ub.h2[g]); \
                } }

            GATHER_CORNER(i00, f00)
            GATHER_CORNER(i01, f01)
            GATHER_CORNER(i10, f10)
            GATHER_CORNER(i11, f11)
            #undef GATHER_CORNER

            #pragma unroll
            for (int c = 0; c < CC; c++) {
                sum[c] += wv[c];
                sq[c]  += wv[c] * wv[c];
            }
        }

        const float invV = 1.f / (float)VV;
        #pragma unroll
        for (int c = 0; c < CC; c++) {
            float mean = sum[c] * invV;
            var[(size_t)c * DD * HW + (size_t)d * HW + pix] =
                __float2half(sq[c] * invV - mean * mean);
        }
    }
}

// ---------------------------------------------------------------------------
// Kernel 3 (v3): 3D conv (16->1, 3x3x3, SAME) on fp16 var.
// Thread t: x-pair p = t%160 (outputs x=2p, 2p+1), y-group ry = t/160,
// rows y0t = ytile*4 + ry*2 .. +1 (YSEG=2), depths d0..d0+3 (CDSEG=4).
// All taps come from three aligned __half2 (32-bit) loads per row — no
// global_load_short_d16 partial-register hazards. 16 outputs/thread.
// ---------------------------------------------------------------------------
__global__ __launch_bounds__(320) void k_conv(const __half* __restrict__ var,
                                              const float* __restrict__ w,
                                              float* __restrict__ cost) {
    // gridDim.x = 512 = 8 chunks of 64; XCD k -> contiguous 32-row y band
    const int orig = blockIdx.x;
    const int wg   = (orig & (NXCD - 1)) * 64 + (orig >> 3);
    const int ytile = wg >> 3;          // 0..63
    const int dtile = wg & 7;           // 0..7

    const int tid = threadIdx.x;
    const int p   = tid % 160;          // x-pair index
    const int ry  = tid / 160;          // 0 or 1
    const int y0t = ytile * 4 + ry * 2; // first output row of this thread
    const int d0  = dtile * CDSEG;

    float acc[YSEG][CDSEG][2];
    #pragma unroll
    for (int dy = 0; dy < YSEG; dy++)
        #pragma unroll
        for (int o = 0; o < CDSEG; o++) { acc[dy][o][0] = 0.f; acc[dy][o][1] = 0.f; }

    const bool plok = (p > 0), prok = (p < 159);

    for (int c = 0; c < CC; c++) {
        float wr[27];
        #pragma unroll
        for (int j = 0; j < 27; j++) wr[j] = w[c * 27 + j];   // uniform -> SGPR

        const __half* base = var + (size_t)c * DD * HW;

        #pragma unroll
        for (int s = 0; s < CDSEG + 2; s++) {
            const int dd = d0 - 1 + s;
            if (dd < 0 || dd >= DD) continue;               // uniform branch

            // window rows y0t-1 .. y0t+2 ; keep only the 4 needed lanes:
            // A1 = half at x=2p-1, B0 = 2p, B1 = 2p+1, C0 = 2p+2
            float A1[YSEG + 2], B0[YSEG + 2], B1[YSEG + 2], C0[YSEG + 2];
            #pragma unroll
            for (int r = 0; r < YSEG + 2; r++) {
                const int yy = y0t - 1 + r;
                const bool vok = (yy >= 0 && yy < HH);       // per-thread
                const int yyc = min(max(yy, 0), HH - 1);
                const __half2* r2 = (const __half2*)(base + (size_t)dd * HW + (size_t)yyc * WW);
                __half2 A = plok ? r2[p - 1] : __floats2half2_rn(0.f, 0.f);
                __half2 B = r2[p];
                __half2 Cv = prok ? r2[p + 1] : __floats2half2_rn(0.f, 0.f);
                const float z = vok ? 1.f : 0.f;
                A1[r] = z * __high2float(A);
                B0[r] = z * __low2float(B);
                B1[r] = z * __high2float(B);
                C0[r] = z * __low2float(Cv);
            }

            #pragma unroll
            for (int kd = 0; kd < 3; kd++) {
                const int o = s - kd;
                if (o < 0 || o >= CDSEG) continue;           // compile-time
                const float* k9 = wr + kd * 9;
                #pragma unroll
                for (int dy = 0; dy < YSEG; dy++) {
                    float a0 = 0.f, a1 = 0.f;
                    #pragma unroll
                    for (int ky = 0; ky < 3; ky++) {
                        const int r = dy + ky;
                        a0 += k9[ky*3+0]*A1[r] + k9[ky*3+1]*B0[r] + k9[ky*3+2]*B1[r];
                        a1 += k9[ky*3+0]*B0[r] + k9[ky*3+1]*B1[r] + k9[ky*3+2]*C0[r];
                    }
                    acc[dy][o][0] += a0;
                    acc[dy][o][1] += a1;
                }
            }
        }
    }

    #pragma unroll
    for (int dy = 0; dy < YSEG; dy++) {
        const int y = y0t + dy;
        #pragma unroll
        for (int o = 0; o < CDSEG; o++) {
            float2* co = (float2*)(cost + (size_t)(d0 + o) * HW + (size_t)y * WW);
            float2 val; val.x = acc[dy][o][0]; val.y = acc[dy][o][1];
            co[p] = val;
        }
    }
}

// ---------------------------------------------------------------------------
// Kernel 4: softmax over D + depth regression + confidence.
// out layout: [0,HW) depth | [HW,2HW) conf | [2HW, 2HW+D*HW) prob
// ---------------------------------------------------------------------------
__global__ __launch_bounds__(256) void k_softmax(const float* __restrict__ cost,
                                                 const float* __restrict__ depth_vals,
                                                 float* __restrict__ out) {
    const int idx = blockIdx.x * blockDim.x + threadIdx.x;
    if (idx >= HW) return;

    float c[DD];
    float m = -INFINITY;
    #pragma unroll
    for (int d = 0; d < DD; d++) {
        c[d] = cost[(size_t)d * HW + idx];
        m = fmaxf(m, c[d]);
    }
    float s = 0.f;
    #pragma unroll
    for (int d = 0; d < DD; d++) {
        c[d] = expf(c[d] - m);
        s += c[d];
    }
    const float inv = 1.f / s;

    float depth = 0.f, di_f = 0.f;
    #pragma unroll
    for (int d = 0; d < DD; d++) {
        float p = c[d] * inv;
        c[d] = p;
        out[2 * HW + (size_t)d * HW + idx] = p;
        depth += p * depth_vals[(size_t)d * HW + idx];
        di_f  += p * (float)d;
    }
    out[idx] = depth;

    int di = (int)di_f;
    di = min(max(di, 0), DD - 1);
    float cur = 0.f, nxt = 0.f;
    #pragma unroll
    for (int d = 0; d < DD; d++) {
        if (d == di)     cur = c[d];
        if (d == di + 1) nxt = c[d];
    }
    out[HW + idx] = cur + nxt;   // nxt stays 0 when di == DD-1
}

// ---------------------------------------------------------------------------
extern "C" void kernel_launch(void* const* d_in, const int* in_sizes, int n_in,
                              void* d_out, int out_size, void* d_ws, size_t ws_size,
                              hipStream_t stream) {
    const float* features = (const float*)d_in[0];
    const float* projs    = (const float*)d_in[1];
    const float* depthv   = (const float*)d_in[2];
    const float* regw     = (const float*)d_in[3];
    float* out = (float*)d_out;

    const size_t tf_elems  = (size_t)VV * HW * CC;       // 6.55M halves (13.1 MB)
    // var: CC*DD*HW halves (83.9 MB)

    float*  M    = (float*)d_ws;                         // 48 floats used
    __half* tf   = (__half*)((char*)d_ws + 4096);
    __half* var  = tf + tf_elems;
    float*  cost = (float*)tf;                           // tf dead after k_var (13.1 >= 10.5 MB)

    k_setup<<<1, 64, 0, stream>>>(projs, M);
    k_transpose<<<(VV * HW + 255) / 256, 256, 0, stream>>>(features, tf);

    k_var_t<<<HH * (DD / ND), WW, 0, stream>>>(tf, depthv, M, var);

    k_conv<<<(HH / (YSEG * 2)) * (DD / CDSEG), WW, 0, stream>>>(var, regw, cost);

    k_softmax<<<(HW + 255) / 256, 256, 0, stream>>>(cost, depthv, out);
}